// Round 1
// 553.728 us; speedup vs baseline: 1.7056x; 1.7056x over previous
//
#include <hip/hip_runtime.h>

// Problem constants: B=2,H=32 -> BH=64; G=C=2048 -> N=4096; D=F=128.
constexpr int BHn = 64;
constexpr int Gn  = 2048;
constexpr int Nn  = 4096;
constexpr int Dn  = 128;

// ---------------- 1. per-(b,h) bitonic sort of 4096 (score, idx) pairs ----------------
// Descending by score, tie-break ascending index (== stable descending sort).
// Comparator-indexed: 2048 comparators per pass, 2 per thread.
__global__ __launch_bounds__(1024) void sort_kernel(
    const float* __restrict__ heap_score, const float* __restrict__ win_score,
    float* __restrict__ out_score, int* __restrict__ top_idx, int* __restrict__ bot_idx)
{
    __shared__ float ss[Nn];
    __shared__ int   si[Nn];
    const int bh = blockIdx.x;
    for (int i = threadIdx.x; i < Nn; i += 1024) {
        ss[i] = (i < Gn) ? heap_score[bh * Gn + i] : win_score[bh * Gn + (i - Gn)];
        si[i] = i;
    }
    __syncthreads();
    for (int klog = 1; klog <= 12; ++klog) {
        const int k = 1 << klog;
        for (int jlog = klog - 1; jlog >= 0; --jlog) {
            const int j = 1 << jlog;
#pragma unroll
            for (int u = 0; u < 2; ++u) {
                int c = threadIdx.x + u * 1024;            // comparator id [0,2048)
                int i = ((c >> jlog) << (jlog + 1)) | (c & (j - 1));
                int ixj = i | j;
                float a = ss[i], b = ss[ixj];
                int ia = si[i], ib = si[ixj];
                bool a_first = (a > b) || (a == b && ia < ib);
                if (a_first != ((i & k) == 0)) {
                    ss[i] = b; ss[ixj] = a; si[i] = ib; si[ixj] = ia;
                }
            }
            __syncthreads();
        }
    }
    for (int i = threadIdx.x; i < Gn; i += 1024) {
        out_score[bh * Gn + i] = ss[i];
        top_idx[bh * Gn + i]   = si[i];
        bot_idx[bh * Gn + i]   = si[Gn + i];
    }
}

// ---------------- 2. zero-init (fallback atomic path only) ----------------
__global__ void zero_kernel(float* __restrict__ p, int n)
{
    int i = blockIdx.x * blockDim.x + threadIdx.x;
    if (i < n) p[i] = 0.f;
}

// ---------------- 3. gather top-2048 rows of K, V, FK ----------------
__global__ __launch_bounds__(256) void gather_kernel(
    const float4* __restrict__ K_top, const float4* __restrict__ V_top, const float4* __restrict__ FK_top,
    const float4* __restrict__ K_win, const float4* __restrict__ V_win, const float4* __restrict__ FK_win,
    const int* __restrict__ top_idx, float4* __restrict__ out)
{
    const int base = blockIdx.x * 1024 + threadIdx.x;
#pragma unroll
    for (int kk = 0; kk < 4; ++kk) {
        int w = base + kk * 256;                 // [0, 3*2^22)
        int c4     = w & 31;
        int within = w & (4194304 - 1);          // 2^22 per array
        int bh     = within >> 16;               // 2048*32 float4 per bh
        int g      = (within >> 5) & 2047;
        int arr    = w >> 22;                    // 0:K 1:V 2:FK
        int idx = top_idx[bh * Gn + g];
        const float4* tsrc = (arr == 0) ? K_top : (arr == 1) ? V_top : FK_top;
        const float4* wsrc = (arr == 0) ? K_win : (arr == 1) ? V_win : FK_win;
        const float4* src = (idx < Gn)
            ? tsrc + (size_t)(bh * Gn + idx) * 32
            : wsrc + (size_t)(bh * Gn + (idx - Gn)) * 32;
        out[(size_t)w] = src[c4];
    }
}

// ---------------- 4a. split-K partial H_sum / S_sum (NO atomics) ----------------
// Grid: BHn << chshift blocks; each block owns (bh, chunk) and writes a private
// 128x128 partial + 128-wide S partial to workspace with plain float4 stores.
// Per-thread tile is a 4+4 column split (td*4 and td*4+64): the 16 distinct
// lane addresses per LDS read cover 256 contiguous bytes -> conflict-free
// (the old (t&15)*8 layout hit only even 16B granules -> 2x bank serialization).
__global__ __launch_bounds__(256, 4) void hsum_partial_kernel(
    const float* __restrict__ V_top, const float* __restrict__ V_win,
    const float* __restrict__ FK_top, const float* __restrict__ FK_win,
    const int* __restrict__ bot_idx,
    float* __restrict__ Hpart, float* __restrict__ Spart, int chshift)
{
    __shared__ float fk_s[32 * Dn];
    __shared__ float v_s[32 * Dn];
    const int nch   = 1 << chshift;
    const int bh    = blockIdx.x >> chshift;
    const int chunk = blockIdx.x & (nch - 1);
    const int t  = threadIdx.x;
    const int tf = t >> 4;     // f-tile row group (0..15)
    const int td = t & 15;     // d-tile col group (0..15)
    const int rl = t >> 5;     // row sub-index for staging loads (0..7)
    const int c4 = t & 31;     // float4 column for staging loads

    float acc[8][8];
#pragma unroll
    for (int i = 0; i < 8; ++i)
#pragma unroll
        for (int j = 0; j < 8; ++j) acc[i][j] = 0.f;
    float s_acc = 0.f;

    const int rows = Gn >> chshift;           // rows per chunk
    const int nst  = rows >> 5;               // stages of 32 rows
    const int* bidx = bot_idx + bh * Gn + chunk * rows;

    for (int stage = 0; stage < nst; ++stage) {
        __syncthreads();
        // Stage 32 rows of FK and V (coalesced float4, 8 independent loads/thread).
#pragma unroll
        for (int rr = 0; rr < 4; ++rr) {
            int r = rr * 8 + rl;                       // 0..31
            int idx = bidx[stage * 32 + r];
            const float4* fsrc;
            const float4* vsrc;
            if (idx < Gn) {
                fsrc = (const float4*)(FK_top + ((size_t)bh * Gn + idx) * Dn);
                vsrc = (const float4*)(V_top  + ((size_t)bh * Gn + idx) * Dn);
            } else {
                fsrc = (const float4*)(FK_win + ((size_t)bh * Gn + idx - Gn) * Dn);
                vsrc = (const float4*)(V_win  + ((size_t)bh * Gn + idx - Gn) * Dn);
            }
            ((float4*)(fk_s + r * Dn))[c4] = fsrc[c4];
            ((float4*)(v_s  + r * Dn))[c4] = vsrc[c4];
        }
        __syncthreads();
#pragma unroll 8
        for (int r = 0; r < 32; ++r) {
            float4 fa = *(const float4*)&fk_s[r * Dn + tf * 4];
            float4 fb = *(const float4*)&fk_s[r * Dn + tf * 4 + 64];
            float4 va = *(const float4*)&v_s[r * Dn + td * 4];
            float4 vb = *(const float4*)&v_s[r * Dn + td * 4 + 64];
            float fr[8] = {fa.x, fa.y, fa.z, fa.w, fb.x, fb.y, fb.z, fb.w};
            float vr[8] = {va.x, va.y, va.z, va.w, vb.x, vb.y, vb.z, vb.w};
#pragma unroll
            for (int i = 0; i < 8; ++i)
#pragma unroll
                for (int j = 0; j < 8; ++j) acc[i][j] += fr[i] * vr[j];
        }
        if (t < 128) {            // wave-uniform branch (waves 0,1)
#pragma unroll 8
            for (int r = 0; r < 32; ++r) s_acc += fk_s[r * Dn + t];
        }
    }

    // Private partial write: coalesced float4 stores, no atomics.
    float* Hp = Hpart + ((size_t)bh * nch + chunk) * (Dn * Dn);
#pragma unroll
    for (int i = 0; i < 8; ++i) {
        int frow = tf * 4 + ((i >> 2) << 6) + (i & 3);   // tf*4 + {0..3} / +64
        float4 lo = make_float4(acc[i][0], acc[i][1], acc[i][2], acc[i][3]);
        float4 hi = make_float4(acc[i][4], acc[i][5], acc[i][6], acc[i][7]);
        *(float4*)(Hp + (size_t)frow * Dn + td * 4)      = lo;
        *(float4*)(Hp + (size_t)frow * Dn + td * 4 + 64) = hi;
    }
    if (t < 128) Spart[((size_t)bh * nch + chunk) * Dn + t] = s_acc;
}

// ---------------- 4b. reduce partials -> H_out, S_out ----------------
// Writes every output element (d_out is poisoned), so no zero pass needed.
__global__ __launch_bounds__(256) void reduce_kernel(
    const float* __restrict__ Hpart, const float* __restrict__ Spart,
    float* __restrict__ H_out, float* __restrict__ S_out, int nch)
{
    const int H_TOT = BHn * Dn * Dn;                 // 1048576
    int o = blockIdx.x * 256 + threadIdx.x;
    if (o < H_TOT) {
        int bh = o >> 14;                            // Dn*Dn = 16384
        int e  = o & 16383;
        const float* p = Hpart + (size_t)bh * nch * (Dn * Dn) + e;
        float s = 0.f;
        for (int c = 0; c < nch; ++c) s += p[(size_t)c * (Dn * Dn)];
        H_out[o] = s;
    } else {
        int o2 = o - H_TOT;
        if (o2 < BHn * Dn) {
            int bh = o2 >> 7;
            int e  = o2 & 127;
            const float* p = Spart + (size_t)bh * nch * Dn + e;
            float s = 0.f;
            for (int c = 0; c < nch; ++c) s += p[(size_t)c * Dn];
            S_out[o2] = s;
        }
    }
}

// ---------------- 4c. fallback: original atomic hsum (if ws too small) ----------------
__global__ __launch_bounds__(256, 4) void hsum_atomic_kernel(
    const float* __restrict__ V_top, const float* __restrict__ V_win,
    const float* __restrict__ FK_top, const float* __restrict__ FK_win,
    const int* __restrict__ bot_idx,
    float* __restrict__ H_out, float* __restrict__ S_out)
{
    __shared__ float fk_s[32 * Dn];
    __shared__ float v_s[32 * Dn];
    const int bh    = blockIdx.x >> 4;
    const int chunk = blockIdx.x & 15;
    const int t  = threadIdx.x;
    const int f0 = (t >> 4) << 3;
    const int d0 = (t & 15) << 3;
    const int rl = t >> 5;
    const int c4 = t & 31;

    float acc[8][8];
#pragma unroll
    for (int i = 0; i < 8; ++i)
#pragma unroll
        for (int j = 0; j < 8; ++j) acc[i][j] = 0.f;
    float s_acc = 0.f;

    const int* bidx = bot_idx + bh * Gn + chunk * (Gn / 16);

    for (int stage = 0; stage < 4; ++stage) {
        __syncthreads();
#pragma unroll
        for (int rr = 0; rr < 4; ++rr) {
            int r = rr * 8 + rl;
            int idx = bidx[stage * 32 + r];
            const float4* fsrc;
            const float4* vsrc;
            if (idx < Gn) {
                fsrc = (const float4*)(FK_top + ((size_t)bh * Gn + idx) * Dn);
                vsrc = (const float4*)(V_top  + ((size_t)bh * Gn + idx) * Dn);
            } else {
                fsrc = (const float4*)(FK_win + ((size_t)bh * Gn + idx - Gn) * Dn);
                vsrc = (const float4*)(V_win  + ((size_t)bh * Gn + idx - Gn) * Dn);
            }
            ((float4*)(fk_s + r * Dn))[c4] = fsrc[c4];
            ((float4*)(v_s  + r * Dn))[c4] = vsrc[c4];
        }
        __syncthreads();
#pragma unroll 8
        for (int r = 0; r < 32; ++r) {
            float4 fa = *(const float4*)&fk_s[r * Dn + f0];
            float4 fb = *(const float4*)&fk_s[r * Dn + f0 + 4];
            float4 va = *(const float4*)&v_s[r * Dn + d0];
            float4 vb = *(const float4*)&v_s[r * Dn + d0 + 4];
            float fr[8] = {fa.x, fa.y, fa.z, fa.w, fb.x, fb.y, fb.z, fb.w};
            float vr[8] = {va.x, va.y, va.z, va.w, vb.x, vb.y, vb.z, vb.w};
#pragma unroll
            for (int i = 0; i < 8; ++i)
#pragma unroll
                for (int j = 0; j < 8; ++j) acc[i][j] += fr[i] * vr[j];
        }
        if (t < 128) {
#pragma unroll 8
            for (int r = 0; r < 32; ++r) s_acc += fk_s[r * Dn + t];
        }
    }

    float* Hp = H_out + (size_t)bh * (Dn * Dn);
#pragma unroll
    for (int i = 0; i < 8; ++i)
#pragma unroll
        for (int j = 0; j < 8; ++j)
            atomicAdd(&Hp[(f0 + i) * Dn + d0 + j], acc[i][j]);
    if (t < 128) atomicAdd(&S_out[bh * Dn + t], s_acc);
}

extern "C" void kernel_launch(void* const* d_in, const int* in_sizes, int n_in,
                              void* d_out, int out_size, void* d_ws, size_t ws_size,
                              hipStream_t stream)
{
    const float* K_top      = (const float*)d_in[0];
    const float* V_top      = (const float*)d_in[1];
    const float* FK_top     = (const float*)d_in[2];
    const float* heap_score = (const float*)d_in[3];
    const float* K_win      = (const float*)d_in[4];
    const float* V_win      = (const float*)d_in[5];
    const float* FK_win     = (const float*)d_in[6];
    const float* win_score  = (const float*)d_in[7];

    float* out = (float*)d_out;
    const size_t S_SCORE = (size_t)BHn * Gn;        // 131072
    const size_t S_MAT   = (size_t)BHn * Gn * Dn;   // 16777216
    const size_t S_H     = (size_t)BHn * Dn * Dn;   // 1048576
    float* out_score  = out;
    float* out_gather = out + S_SCORE;               // K_top_new,V_top_new,FK_top_new
    float* H_out      = out + S_SCORE + 3 * S_MAT;
    float* S_out      = H_out + S_H;

    int* top_idx = (int*)d_ws;                       // 131072 ints
    int* bot_idx = top_idx + BHn * Gn;               // 131072 ints (1 MB total)
    const size_t idx_bytes = (size_t)2 * BHn * Gn * sizeof(int);

    sort_kernel<<<BHn, 1024, 0, stream>>>(heap_score, win_score, out_score, top_idx, bot_idx);

    gather_kernel<<<3 * 4194304 / 1024, 256, 0, stream>>>(
        (const float4*)K_top, (const float4*)V_top, (const float4*)FK_top,
        (const float4*)K_win, (const float4*)V_win, (const float4*)FK_win,
        top_idx, (float4*)out_gather);

    // Pick the largest split-K factor whose partial buffers fit in the workspace.
    int chshift = -1;
    for (int cs = 4; cs >= 2; --cs) {
        size_t need = idx_bytes +
                      (size_t)BHn * ((size_t)1 << cs) * (Dn * Dn + Dn) * sizeof(float);
        if (ws_size >= need) { chshift = cs; break; }
    }

    if (chshift >= 0) {
        const int nch = 1 << chshift;
        float* Hpart = (float*)((char*)d_ws + idx_bytes);
        float* Spart = Hpart + (size_t)BHn * nch * (Dn * Dn);
        hsum_partial_kernel<<<BHn << chshift, 256, 0, stream>>>(
            V_top, V_win, FK_top, FK_win, bot_idx, Hpart, Spart, chshift);
        const int tot = (int)(S_H + (size_t)BHn * Dn);
        reduce_kernel<<<(tot + 255) / 256, 256, 0, stream>>>(
            Hpart, Spart, H_out, S_out, nch);
    } else {
        int zn = (int)(S_H + (size_t)BHn * Dn);
        zero_kernel<<<(zn + 255) / 256, 256, 0, stream>>>(H_out, zn);
        hsum_atomic_kernel<<<BHn * 16, 256, 0, stream>>>(
            V_top, V_win, FK_top, FK_win, bot_idx, H_out, S_out);
    }
}